// Round 8
// baseline (978.685 us; speedup 1.0000x reference)
//
#include <hip/hip_runtime.h>
#include <stdint.h>

#define NBATCH 32
#define CAP    6144            // candidate capacity per segment (expected ~2500)
#define CAP2   512             // sub-bucket capacity (expected ~10)

typedef unsigned long long u64;
typedef unsigned int u32;
typedef float f4 __attribute__((ext_vector_type(4)));

struct WsHdr {
  u64 keysel[NBATCH];  // k-th smallest 56-bit key per segment (rank ndrop)
  int counts[NBATCH];  // segment sizes
  int clo[NBATCH];     // # scores below window per segment
  int ccount[NBATCH];  // candidates in window per segment
  int pad[NBATCH];
};
// ws layout: WsHdr | u64 cand[NBATCH*CAP] (1.5MB)

// monotone float->uint transform
__device__ __forceinline__ u32 ordbits(float s) {
  u32 u = __float_as_uint(s);
  return (u & 0x80000000u) ? ~u : (u | 0x80000000u);
}
__device__ __forceinline__ u32 obL() { return ordbits(0.46f); }
__device__ __forceinline__ u32 obR() { return ordbits(0.54f); }

// ---------------- fast path (4 kernels total) ----------------

__global__ void k_zero_hdr(WsHdr* ws) {
  int t = threadIdx.x;
  if (t < NBATCH) { ws->counts[t] = 0; ws->clo[t] = 0; ws->ccount[t] = 0; }
}

// single pass: per-segment count, below-window count, window candidate compaction.
// batch sorted -> waves are batch-uniform -> 2 LDS atomics per wave.
__global__ void k_pass1(const int* __restrict__ batch, const float* __restrict__ scores,
                        int n, WsHdr* ws, u64* __restrict__ cand) {
  __shared__ int h[NBATCH], hl[NBATCH];
  if (threadIdx.x < NBATCH) { h[threadIdx.x] = 0; hl[threadIdx.x] = 0; }
  __syncthreads();
  int i = blockIdx.x * blockDim.x + threadIdx.x;
  if (i < n) {
    int b = batch[i];
    u32 ob = ordbits(scores[i]);
    bool lo = ob < obL();
    u64 act = __ballot(1);
    int lead = (int)__ffsll((long long)act) - 1;
    int b0 = __shfl(b, lead, 64);
    bool uni = (__ballot(b == b0) == act);
    if (uni) {
      u64 lom = __ballot(lo);
      if ((threadIdx.x & 63) == lead) {
        atomicAdd(&h[b0], (int)__popcll(act));
        if (lom) atomicAdd(&hl[b0], (int)__popcll(lom));
      }
    } else {
      atomicAdd(&h[b], 1);
      if (lo) atomicAdd(&hl[b], 1);
    }
    if (!lo && ob < obR()) {
      int p = atomicAdd(&ws->ccount[b], 1);
      if (p < CAP)
        cand[(size_t)b * CAP + p] = ((u64)ob << 24) | (u32)i;   // global index key
    }
  }
  __syncthreads();
  if (threadIdx.x < NBATCH) {
    if (h[threadIdx.x])  atomicAdd(&ws->counts[threadIdx.x], h[threadIdx.x]);
    if (hl[threadIdx.x]) atomicAdd(&ws->clo[threadIdx.x], hl[threadIdx.x]);
  }
}

// one block per segment: select key of rank ndrop. Fast path: bucket-rank among
// window candidates. Slow exact fallback: in-block 8-bit radix over the segment.
__global__ void k_final(const float* __restrict__ scores, WsHdr* ws,
                        const u64* __restrict__ cand) {
  __shared__ u64 ck[CAP];      // 48KB
  __shared__ u64 ck2[CAP2];    // 4KB
  __shared__ int sc[256];
  __shared__ int sh_w, sh_krem, sh_m2;
  int b = blockIdx.x, t = threadIdx.x;
  int cnt = ws->counts[b];
  if (cnt == 0) { if (t == 0) ws->keysel[b] = 0ull; return; }
  int krem = cnt >> 1;                       // ndrop = floor(cnt*0.5) exact
  int m = ws->ccount[b];
  int krem2 = krem - ws->clo[b];
  bool fast = (krem2 >= 0) && (krem2 < m) && (m <= CAP);

  if (fast) {
    const u32 span = obR() - obL();
    for (int j = t; j < m; j += 256) ck[j] = cand[(size_t)b * CAP + j];
    sc[t] = 0;
    if (t == 0) sh_m2 = 0;
    __syncthreads();
    for (int j = t; j < m; j += 256) {
      u32 ob = (u32)(ck[j] >> 24);
      u32 bk = (u32)(((u64)(ob - obL()) << 8) / span);
      atomicAdd(&sc[bk], 1);
    }
    __syncthreads();
    int own = sc[t];
    for (int off = 1; off < 256; off <<= 1) {      // Hillis-Steele inclusive scan
      int v = (t >= off) ? sc[t - off] : 0;
      __syncthreads(); sc[t] += v; __syncthreads();
    }
    int excl = sc[t] - own;
    if (krem2 >= excl && krem2 < excl + own) { sh_w = t; sh_krem = krem2 - excl; }
    __syncthreads();
    int W = sh_w, krem3 = sh_krem;
    for (int j = t; j < m; j += 256) {             // compact winning bucket
      u32 ob = (u32)(ck[j] >> 24);
      u32 bk = (u32)(((u64)(ob - obL()) << 8) / span);
      if ((int)bk == W) {
        int p = atomicAdd(&sh_m2, 1);
        if (p < CAP2) ck2[p] = ck[j];
      }
    }
    __syncthreads();
    int m2 = sh_m2;
    if (m2 <= CAP2) {
      for (int j = t; j < m2; j += 256) {
        u64 key = ck2[j];
        int r = 0;
        for (int q = 0; q < m2; ++q) r += (ck2[q] < key);   // keys distinct
        if (r == krem3) ws->keysel[b] = key;
      }
      return;
    }
    __syncthreads();   // fall through to radix if sub-bucket overflowed
  }

  // exact in-block radix select over segment [start, start+cnt)
  if (t == 0) { int acc = 0; for (int x = 0; x < b; ++x) acc += ws->counts[x]; sh_w = acc; }
  __syncthreads();
  int start = sh_w;
  u64 prefix = 0; int kr = krem;
  for (int shift = 48; shift >= 0; shift -= 8) {
    sc[t] = 0;
    __syncthreads();
    for (int idx = t; idx < cnt; idx += 256) {
      u64 key = ((u64)ordbits(scores[start + idx]) << 24) | (u32)(start + idx);
      if ((key >> (shift + 8)) == prefix) atomicAdd(&sc[(int)((key >> shift) & 255)], 1);
    }
    __syncthreads();
    int own = sc[t];
    for (int off = 1; off < 256; off <<= 1) {
      int v = (t >= off) ? sc[t - off] : 0;
      __syncthreads(); sc[t] += v; __syncthreads();
    }
    int excl = sc[t] - own;
    if (kr >= excl && kr < excl + own) { sh_w = t; sh_krem = kr - excl; }
    __syncthreads();
    prefix = (prefix << 8) | (u32)sh_w;
    kr = sh_krem;
    __syncthreads();
  }
  if (t == 0) ws->keysel[b] = prefix;
}

// ---------------- apply: key uses global index, no starts needed ----------------
__global__ void k_apply(const f4* __restrict__ feats4,
                        const int* __restrict__ batch,
                        const float* __restrict__ scores,
                        const WsHdr* __restrict__ ws,
                        f4* __restrict__ out4, int n) {
  int t = threadIdx.x;
  int pl = t >> 4, ch = t & 15;
  int i = blockIdx.x * 16 + pl;
  if (i >= n) return;
  int b = batch[i];                         // 16-lane broadcast loads
  u64 key = ((u64)ordbits(scores[i]) << 24) | (u32)i;
  size_t off = (size_t)i * 16 + (size_t)ch;
  f4 v;
  if (key >= ws->keysel[b]) {
    v = __builtin_nontemporal_load(feats4 + off);
  } else {
    v = (f4){0.f, 0.f, 0.f, 0.f};
  }
  __builtin_nontemporal_store(v, out4 + off);
}

// ---------------- fallback chain (tiny ws): exact, global-idx keys ----------------

__global__ void k_hist_fb(const int* __restrict__ batch, int n, WsHdr* ws) {
  __shared__ int h[NBATCH];
  if (threadIdx.x < NBATCH) h[threadIdx.x] = 0;
  __syncthreads();
  int stride = gridDim.x * blockDim.x;
  for (int i = blockIdx.x * blockDim.x + threadIdx.x; i < n; i += stride)
    atomicAdd(&h[batch[i]], 1);
  __syncthreads();
  if (threadIdx.x < NBATCH) atomicAdd(&ws->counts[threadIdx.x], h[threadIdx.x]);
}

__global__ void k_select_fb(const float* __restrict__ scores, WsHdr* ws) {
  __shared__ u32 hist[256];
  __shared__ u64 sh_prefix;
  __shared__ int sh_krem, sh_start;
  int b = blockIdx.x, t = threadIdx.x;
  if (t == 0) {
    int acc = 0; for (int x = 0; x < b; ++x) acc += ws->counts[x];
    sh_start = acc; sh_prefix = 0ull; sh_krem = ws->counts[b] >> 1;
  }
  __syncthreads();
  int start = sh_start, cnt = ws->counts[b];
  if (cnt == 0) { if (t == 0) ws->keysel[b] = 0ull; return; }
  for (int shift = 48; shift >= 0; shift -= 8) {
    for (int j = t; j < 256; j += blockDim.x) hist[j] = 0;
    __syncthreads();
    u64 prefix = sh_prefix;
    for (int idx = t; idx < cnt; idx += blockDim.x) {
      u64 key = ((u64)ordbits(scores[start + idx]) << 24) | (u32)(start + idx);
      if ((key >> (shift + 8)) == prefix)
        atomicAdd(&hist[(u32)(key >> shift) & 255u], 1u);
    }
    __syncthreads();
    if (t == 0) {
      int krem = sh_krem;
      u32 cum = 0, sel = 255;
      for (int j = 0; j < 256; ++j) {
        u32 c = hist[j];
        if ((u32)krem < cum + c) { sel = (u32)j; krem -= (int)cum; break; }
        cum += c;
      }
      sh_prefix = (sh_prefix << 8) | sel;
      sh_krem = krem;
    }
    __syncthreads();
  }
  if (t == 0) ws->keysel[b] = sh_prefix;
}

extern "C" void kernel_launch(void* const* d_in, const int* in_sizes, int n_in,
                              void* d_out, int out_size, void* d_ws, size_t ws_size,
                              hipStream_t stream) {
  const float* feats  = (const float*)d_in[0];
  const int*   batch  = (const int*)d_in[1];
  const float* scores = (const float*)d_in[2];
  float* out = (float*)d_out;
  int n = in_sizes[1];
  WsHdr* ws = (WsHdr*)d_ws;

  const size_t cand_bytes = (size_t)NBATCH * CAP * sizeof(u64);   // 1.5 MB
  const size_t need = sizeof(WsHdr) + cand_bytes;

  if (ws_size >= need) {
    u64* cand = (u64*)((char*)d_ws + sizeof(WsHdr));
    int pb = (n + 255) / 256;
    k_zero_hdr<<<1, 64, 0, stream>>>(ws);
    k_pass1   <<<pb, 256, 0, stream>>>(batch, scores, n, ws, cand);
    k_final   <<<NBATCH, 256, 0, stream>>>(scores, ws, cand);
  } else {
    k_zero_hdr <<<1, 64, 0, stream>>>(ws);
    k_hist_fb  <<<1024, 256, 0, stream>>>(batch, n, ws);
    k_select_fb<<<NBATCH, 256, 0, stream>>>(scores, ws);
  }

  int blocks = (n + 15) / 16;   // 16 rows per block, 16 float4 per row
  k_apply<<<blocks, 256, 0, stream>>>((const f4*)feats, batch, scores, ws,
                                      (f4*)out, n);
}

// Round 9
// 133.057 us; speedup vs baseline: 7.3554x; 7.3554x over previous
//
#include <hip/hip_runtime.h>
#include <stdint.h>

#define NBATCH 32
#define NSUB   64              // sub-counters per segment (contention spreading)
#define SUBCAP 128             // candidate slots per (segment,sub); expected ~39
#define CAPTOT 6144            // LDS gather capacity; expected total ~2500
#define CAP2   512             // sub-bucket capacity in rank select

typedef unsigned long long u64;
typedef unsigned int u32;
typedef float f4 __attribute__((ext_vector_type(4)));

struct WsHdr {
  u64 keysel[NBATCH];   // k-th smallest 56-bit key per segment
  int counts[NBATCH];   // fallback path only
};
// ws: WsHdr | u32 meta[NBATCH*NSUB*16] (128KB, one 64B line per (b,sub):
//     [0]=count,[1]=below-window,[2]=cand-count) | u64 cand[NBATCH*NSUB*SUBCAP] (2MB)

__device__ __forceinline__ u32 ordbits(float s) {
  u32 u = __float_as_uint(s);
  return (u & 0x80000000u) ? ~u : (u | 0x80000000u);
}
__device__ __forceinline__ u32 obL() { return ordbits(0.46f); }
__device__ __forceinline__ u32 obR() { return ordbits(0.54f); }

// ---------------- fast path (4 kernels) ----------------

__global__ void k_zero(u32* __restrict__ p, int nwords) {
  int stride = gridDim.x * blockDim.x;
  for (int i = blockIdx.x * blockDim.x + threadIdx.x; i < nwords; i += stride)
    p[i] = 0u;
}

// one pass: per-(b,sub) count / below-window count / window candidate compaction.
// All global atomics go to (b,sub)-private 64B lines -> no same-line contention.
__global__ void k_pass1(const int* __restrict__ batch, const float* __restrict__ scores,
                        int n, u32* __restrict__ meta, u64* __restrict__ cand) {
  __shared__ int h[NBATCH], hl[NBATCH];
  if (threadIdx.x < NBATCH) { h[threadIdx.x] = 0; hl[threadIdx.x] = 0; }
  __syncthreads();
  int sub = blockIdx.x & (NSUB - 1);
  int i = blockIdx.x * blockDim.x + threadIdx.x;
  if (i < n) {
    int b = batch[i];
    u32 ob = ordbits(scores[i]);
    bool lo = ob < obL();
    u64 act = __ballot(1);
    int lead = (int)__ffsll((long long)act) - 1;
    int b0 = __shfl(b, lead, 64);
    bool uni = (__ballot(b == b0) == act);
    if (uni) {
      u64 lom = __ballot(lo);
      if ((threadIdx.x & 63) == lead) {
        atomicAdd(&h[b0], (int)__popcll(act));
        if (lom) atomicAdd(&hl[b0], (int)__popcll(lom));
      }
    } else {
      atomicAdd(&h[b], 1);
      if (lo) atomicAdd(&hl[b], 1);
    }
    if (!lo && ob < obR()) {
      int cell = (b << 6) | sub;
      int p = (int)atomicAdd(&meta[(cell << 4) + 2], 1u);
      if (p < SUBCAP)
        cand[(size_t)cell * SUBCAP + p] = ((u64)ob << 24) | (u32)i;  // global-idx key
    }
  }
  __syncthreads();
  if (threadIdx.x < NBATCH) {
    int cell = (threadIdx.x << 6) | sub;
    if (h[threadIdx.x])  atomicAdd(&meta[(cell << 4) + 0], (u32)h[threadIdx.x]);
    if (hl[threadIdx.x]) atomicAdd(&meta[(cell << 4) + 1], (u32)hl[threadIdx.x]);
  }
}

// one block per segment: gather sub-lists, bucket-rank the k-th key.
// Exact in-block radix fallback if window missed or any sub overflowed.
__global__ void k_final(const float* __restrict__ scores, const u32* __restrict__ meta,
                        const u64* __restrict__ cand, WsHdr* ws) {
  __shared__ u64 ck[CAPTOT];     // 48KB
  __shared__ u64 ck2[CAP2];      // 4KB
  __shared__ int sc[256];
  __shared__ int moff[NSUB + 1];
  __shared__ int sh_w, sh_krem, sh_m2, sh_cnt, sh_clo, sh_bad, sh_start;
  int b = blockIdx.x, t = threadIdx.x;

  if (t < NSUB) {                           // wave 0 only
    const u32* mp = meta + (((b << 6) | t) << 4);
    int mc = (int)mp[0], ml = (int)mp[1], mw = (int)mp[2];
    u64 bad = __ballot(mw > SUBCAP);
    int v = mw < SUBCAP ? mw : SUBCAP;      // inclusive shfl scan of gatherable counts
    for (int d = 1; d < 64; d <<= 1) { int u = __shfl_up(v, d, 64); if (t >= d) v += u; }
    moff[t + 1] = v; if (t == 0) moff[0] = 0;
    int s1 = mc, s2 = ml;
    for (int off = 32; off > 0; off >>= 1) {
      s1 += __shfl_down(s1, off, 64);
      s2 += __shfl_down(s2, off, 64);
    }
    if (t == 0) { sh_cnt = s1; sh_clo = s2; sh_bad = (bad != 0ull); }
  }
  __syncthreads();
  int cnt = sh_cnt;
  if (cnt == 0) { if (t == 0) ws->keysel[b] = 0ull; return; }
  int krem = cnt >> 1;                      // ndrop = floor(cnt*0.5) exact
  int m = moff[NSUB];
  int krem2 = krem - sh_clo;
  bool fast = !sh_bad && krem2 >= 0 && krem2 < m && m <= CAPTOT;

  if (fast) {
    const u32 span = obR() - obL();
    for (int sub = 0; sub < NSUB; ++sub) {
      int cw = moff[sub + 1] - moff[sub];
      const u64* src = cand + (size_t)((b << 6) | sub) * SUBCAP;
      for (int j = t; j < cw; j += 256) ck[moff[sub] + j] = src[j];
    }
    sc[t] = 0;
    if (t == 0) sh_m2 = 0;
    __syncthreads();
    for (int j = t; j < m; j += 256) {
      u32 ob = (u32)(ck[j] >> 24);
      u32 bk = (u32)(((u64)(ob - obL()) << 8) / span);
      atomicAdd(&sc[bk], 1);
    }
    __syncthreads();
    int own = sc[t];
    for (int off = 1; off < 256; off <<= 1) {       // Hillis-Steele inclusive scan
      int v = (t >= off) ? sc[t - off] : 0;
      __syncthreads(); sc[t] += v; __syncthreads();
    }
    int excl = sc[t] - own;
    if (krem2 >= excl && krem2 < excl + own) { sh_w = t; sh_krem = krem2 - excl; }
    __syncthreads();
    int W = sh_w, krem3 = sh_krem;
    for (int j = t; j < m; j += 256) {              // compact winning bucket
      u32 ob = (u32)(ck[j] >> 24);
      u32 bk = (u32)(((u64)(ob - obL()) << 8) / span);
      if ((int)bk == W) {
        int p = atomicAdd(&sh_m2, 1);
        if (p < CAP2) ck2[p] = ck[j];
      }
    }
    __syncthreads();
    int m2 = sh_m2;
    if (m2 <= CAP2) {
      for (int j = t; j < m2; j += 256) {
        u64 key = ck2[j];
        int r = 0;
        for (int q = 0; q < m2; ++q) r += (ck2[q] < key);   // keys distinct
        if (r == krem3) ws->keysel[b] = key;
      }
      return;
    }
    __syncthreads();   // sub-bucket overflow -> exact radix below
  }

  // exact in-block 8-bit radix select over segment [start, start+cnt)
  {
    int acc = 0;
    for (int idx = t; idx < b * NSUB; idx += 256)
      acc += (int)meta[((idx / NSUB) == (idx / NSUB) ? (((idx / NSUB) << 6) | (idx & (NSUB - 1))) : 0) << 4];
    sc[t] = acc; __syncthreads();
    for (int off = 128; off > 0; off >>= 1) {
      if (t < off) sc[t] += sc[t + off];
      __syncthreads();
    }
    if (t == 0) sh_start = sc[0];
    __syncthreads();
  }
  int start = sh_start;
  u64 prefix = 0; int kr = krem;
  for (int shift = 48; shift >= 0; shift -= 8) {
    sc[t] = 0;
    __syncthreads();
    for (int idx = t; idx < cnt; idx += 256) {
      u64 key = ((u64)ordbits(scores[start + idx]) << 24) | (u32)(start + idx);
      if ((key >> (shift + 8)) == prefix) atomicAdd(&sc[(int)((key >> shift) & 255)], 1);
    }
    __syncthreads();
    int own = sc[t];
    for (int off = 1; off < 256; off <<= 1) {
      int v = (t >= off) ? sc[t - off] : 0;
      __syncthreads(); sc[t] += v; __syncthreads();
    }
    int excl = sc[t] - own;
    if (kr >= excl && kr < excl + own) { sh_w = t; sh_krem = kr - excl; }
    __syncthreads();
    prefix = (prefix << 8) | (u32)sh_w;
    kr = sh_krem;
    __syncthreads();
  }
  if (t == 0) ws->keysel[b] = prefix;
}

// ---------------- apply (global-idx keys; only keysel needed) ----------------
__global__ void k_apply(const f4* __restrict__ feats4,
                        const int* __restrict__ batch,
                        const float* __restrict__ scores,
                        const WsHdr* __restrict__ ws,
                        f4* __restrict__ out4, int n) {
  int t = threadIdx.x;
  int pl = t >> 4, ch = t & 15;
  int i = blockIdx.x * 16 + pl;
  if (i >= n) return;
  int b = batch[i];                         // 16-lane broadcast loads
  u64 key = ((u64)ordbits(scores[i]) << 24) | (u32)i;
  size_t off = (size_t)i * 16 + (size_t)ch;
  f4 v;
  if (key >= ws->keysel[b]) {
    v = __builtin_nontemporal_load(feats4 + off);
  } else {
    v = (f4){0.f, 0.f, 0.f, 0.f};
  }
  __builtin_nontemporal_store(v, out4 + off);
}

// ---------------- fallback chain (tiny ws): exact, global-idx keys ----------------

__global__ void k_zero_hdr(WsHdr* ws) {
  int t = threadIdx.x;
  if (t < NBATCH) ws->counts[t] = 0;
}

__global__ void k_hist_fb(const int* __restrict__ batch, int n, WsHdr* ws) {
  __shared__ int h[NBATCH];
  if (threadIdx.x < NBATCH) h[threadIdx.x] = 0;
  __syncthreads();
  int stride = gridDim.x * blockDim.x;
  for (int i = blockIdx.x * blockDim.x + threadIdx.x; i < n; i += stride)
    atomicAdd(&h[batch[i]], 1);
  __syncthreads();
  if (threadIdx.x < NBATCH) atomicAdd(&ws->counts[threadIdx.x], h[threadIdx.x]);
}

__global__ void k_select_fb(const float* __restrict__ scores, WsHdr* ws) {
  __shared__ u32 hist[256];
  __shared__ u64 sh_prefix;
  __shared__ int sh_krem, sh_start;
  int b = blockIdx.x, t = threadIdx.x;
  if (t == 0) {
    int acc = 0; for (int x = 0; x < b; ++x) acc += ws->counts[x];
    sh_start = acc; sh_prefix = 0ull; sh_krem = ws->counts[b] >> 1;
  }
  __syncthreads();
  int start = sh_start, cnt = ws->counts[b];
  if (cnt == 0) { if (t == 0) ws->keysel[b] = 0ull; return; }
  for (int shift = 48; shift >= 0; shift -= 8) {
    for (int j = t; j < 256; j += blockDim.x) hist[j] = 0;
    __syncthreads();
    u64 prefix = sh_prefix;
    for (int idx = t; idx < cnt; idx += blockDim.x) {
      u64 key = ((u64)ordbits(scores[start + idx]) << 24) | (u32)(start + idx);
      if ((key >> (shift + 8)) == prefix)
        atomicAdd(&hist[(u32)(key >> shift) & 255u], 1u);
    }
    __syncthreads();
    if (t == 0) {
      int krem = sh_krem;
      u32 cum = 0, sel = 255;
      for (int j = 0; j < 256; ++j) {
        u32 c = hist[j];
        if ((u32)krem < cum + c) { sel = (u32)j; krem -= (int)cum; break; }
        cum += c;
      }
      sh_prefix = (sh_prefix << 8) | sel;
      sh_krem = krem;
    }
    __syncthreads();
  }
  if (t == 0) ws->keysel[b] = sh_prefix;
}

extern "C" void kernel_launch(void* const* d_in, const int* in_sizes, int n_in,
                              void* d_out, int out_size, void* d_ws, size_t ws_size,
                              hipStream_t stream) {
  const float* feats  = (const float*)d_in[0];
  const int*   batch  = (const int*)d_in[1];
  const float* scores = (const float*)d_in[2];
  float* out = (float*)d_out;
  int n = in_sizes[1];
  WsHdr* ws = (WsHdr*)d_ws;

  const size_t meta_bytes = (size_t)NBATCH * NSUB * 16 * sizeof(u32);      // 128 KB
  const size_t cand_bytes = (size_t)NBATCH * NSUB * SUBCAP * sizeof(u64);  // 2 MB
  const size_t need = sizeof(WsHdr) + meta_bytes + cand_bytes;

  if (ws_size >= need) {
    u32* meta = (u32*)((char*)d_ws + sizeof(WsHdr));
    u64* cand = (u64*)((char*)d_ws + sizeof(WsHdr) + meta_bytes);
    int nwords = (int)((sizeof(WsHdr) + meta_bytes) / 4);
    int pb = (n + 255) / 256;
    k_zero  <<<128, 256, 0, stream>>>((u32*)d_ws, nwords);
    k_pass1 <<<pb, 256, 0, stream>>>(batch, scores, n, meta, cand);
    k_final <<<NBATCH, 256, 0, stream>>>(scores, meta, cand, ws);
  } else {
    k_zero_hdr <<<1, 64, 0, stream>>>(ws);
    k_hist_fb  <<<1024, 256, 0, stream>>>(batch, n, ws);
    k_select_fb<<<NBATCH, 256, 0, stream>>>(scores, ws);
  }

  int blocks = (n + 15) / 16;   // 16 rows per block, 16 float4 per row
  k_apply<<<blocks, 256, 0, stream>>>((const f4*)feats, batch, scores, ws,
                                      (f4*)out, n);
}

// Round 10
// 130.273 us; speedup vs baseline: 7.5126x; 1.0214x over previous
//
#include <hip/hip_runtime.h>
#include <stdint.h>

#define NBATCH 32
#define VPT    4
#define BPTS   1024            // points per pass1 block (256*VPT)
#define CAP_BLK 256            // candidate slots per block (expected ~82)
#define MSTRIDE 72             // u32s per block meta row: cnt[32] clo[32] candcnt pad[7]
#define CAPTOT 6144            // LDS gather capacity (expected ~2500/segment)
#define CAP2   512             // sub-bucket capacity in rank select

typedef unsigned long long u64;
typedef unsigned int u32;
typedef float f4 __attribute__((ext_vector_type(4)));

struct WsHdr {
  u64 keysel[NBATCH];   // k-th smallest 56-bit key per segment (b-byte masked off)
  int counts[NBATCH];   // fallback path only
};
// ws: WsHdr | u32 meta[nblk*MSTRIDE] | u64 cand[nblk*CAP_BLK]
// Nothing is pre-zeroed: every meta row is fully written by its owning block;
// cand slots are only read up to the stored (clamped) count.

__device__ __forceinline__ u32 ordbits(float s) {
  u32 u = __float_as_uint(s);
  return (u & 0x80000000u) ? ~u : (u | 0x80000000u);
}
__device__ __forceinline__ u32 obL() { return ordbits(0.46f); }
__device__ __forceinline__ u32 obR() { return ordbits(0.54f); }

// ---------------- fast path (3 kernels, no zeroing, no global atomics) ------------

__global__ void k_pass1(const int* __restrict__ batch, const float* __restrict__ scores,
                        int n, u32* __restrict__ meta, u64* __restrict__ cand) {
  __shared__ int hc[NBATCH], hl[NBATCH];
  __shared__ int sc[256];
  int t = threadIdx.x, blk = blockIdx.x;
  if (t < NBATCH) { hc[t] = 0; hl[t] = 0; }
  __syncthreads();

  u64 wk[VPT]; int wcnt = 0;
  int i0 = blk * BPTS + t * VPT;
  #pragma unroll
  for (int v = 0; v < VPT; ++v) {
    int i = i0 + v;
    if (i < n) {
      int b = batch[i];
      u32 ob = ordbits(scores[i]);
      bool lo = ob < obL();
      u64 act = __ballot(1);
      int lead = (int)__ffsll((long long)act) - 1;
      int b0 = __shfl(b, lead, 64);
      bool uni = (__ballot(b == b0) == act);
      if (uni) {
        u64 lom = __ballot(lo);
        if ((t & 63) == lead) {
          atomicAdd(&hc[b0], (int)__popcll(act));
          if (lom) atomicAdd(&hl[b0], (int)__popcll(lom));
        }
      } else {
        atomicAdd(&hc[b], 1);
        if (lo) atomicAdd(&hl[b], 1);
      }
      if (!lo && ob < obR())
        wk[wcnt++] = ((u64)(u32)b << 56) | ((u64)ob << 24) | (u32)i;
    }
  }
  // block-wide compaction of window candidates (LDS scan, deterministic)
  sc[t] = wcnt; __syncthreads();
  for (int off = 1; off < 256; off <<= 1) {
    int v = (t >= off) ? sc[t - off] : 0;
    __syncthreads(); sc[t] += v; __syncthreads();
  }
  int excl = sc[t] - wcnt;
  int m = sc[255];
  u64* dst = cand + (size_t)blk * CAP_BLK;
  for (int j = 0; j < wcnt; ++j)
    if (excl + j < CAP_BLK) dst[excl + j] = wk[j];
  __syncthreads();
  u32* mrow = meta + (size_t)blk * MSTRIDE;
  if (t < NBATCH) { mrow[t] = (u32)hc[t]; mrow[NBATCH + t] = (u32)hl[t]; }
  if (t == 0) mrow[64] = (u32)m;              // true count (may exceed CAP_BLK)
}

// one block per segment: reduce meta, gather+filter candidates, bucket-rank.
// Exact in-block radix fallback for window miss / overflow (data-independent).
__global__ void k_final(const float* __restrict__ scores, const u32* __restrict__ meta,
                        int nblk, const u64* __restrict__ cand, WsHdr* ws) {
  __shared__ u64 ck[CAPTOT];     // 48KB
  __shared__ u64 ck2[CAP2];      // 4KB
  __shared__ int sc[256];
  __shared__ int sh_w, sh_krem, sh_m, sh_m2, sh_cnt, sh_clo, sh_bad, sh_start;
  int b = blockIdx.x, t = threadIdx.x;

  // reduce cnt/clo/bad over all pass1 blocks (thread-strided)
  {
    int c = 0, l = 0, bad = 0;
    for (int blk = t; blk < nblk; blk += 256) {
      const u32* mrow = meta + (size_t)blk * MSTRIDE;
      u32 cb = mrow[b];
      c += (int)cb;
      l += (int)mrow[NBATCH + b];
      if (cb && mrow[64] > CAP_BLK) bad = 1;
    }
    sc[t] = c; __syncthreads();
    for (int off = 128; off > 0; off >>= 1) { if (t < off) sc[t] += sc[t + off]; __syncthreads(); }
    if (t == 0) sh_cnt = sc[0];
    __syncthreads();
    sc[t] = l; __syncthreads();
    for (int off = 128; off > 0; off >>= 1) { if (t < off) sc[t] += sc[t + off]; __syncthreads(); }
    if (t == 0) sh_clo = sc[0];
    __syncthreads();
    sc[t] = bad; __syncthreads();
    for (int off = 128; off > 0; off >>= 1) { if (t < off) sc[t] |= sc[t + off]; __syncthreads(); }
    if (t == 0) { sh_bad = sc[0]; sh_m = 0; sh_m2 = 0; }
    __syncthreads();
  }
  int cnt = sh_cnt;
  if (cnt == 0) { if (t == 0) ws->keysel[b] = 0ull; return; }
  int krem = cnt >> 1;                        // ndrop = floor(cnt*0.5) exact

  // gather this segment's candidates (filter by top byte), thread-strided blocks
  for (int blk = t; blk < nblk; blk += 256) {
    const u32* mrow = meta + (size_t)blk * MSTRIDE;
    if (mrow[b] == 0) continue;               // no points of b in this block
    int cc = (int)mrow[64]; if (cc > CAP_BLK) cc = CAP_BLK;
    const u64* src = cand + (size_t)blk * CAP_BLK;
    for (int j = 0; j < cc; ++j) {
      u64 s = src[j];
      if ((int)(s >> 56) == b) {
        int p = atomicAdd(&sh_m, 1);
        if (p < CAPTOT) ck[p] = s;
      }
    }
  }
  __syncthreads();
  int m = sh_m;
  int krem2 = krem - sh_clo;
  bool fast = !sh_bad && m <= CAPTOT && krem2 >= 0 && krem2 < m;

  if (fast) {
    const u32 span = obR() - obL();
    sc[t] = 0; __syncthreads();
    for (int j = t; j < m; j += 256) {
      u32 ob = (u32)(ck[j] >> 24);
      u32 bk = (u32)(((u64)(ob - obL()) << 8) / span);
      atomicAdd(&sc[bk], 1);
    }
    __syncthreads();
    int own = sc[t];
    for (int off = 1; off < 256; off <<= 1) {     // Hillis-Steele inclusive scan
      int v = (t >= off) ? sc[t - off] : 0;
      __syncthreads(); sc[t] += v; __syncthreads();
    }
    int excl = sc[t] - own;
    if (krem2 >= excl && krem2 < excl + own) { sh_w = t; sh_krem = krem2 - excl; }
    __syncthreads();
    int W = sh_w, krem3 = sh_krem;
    for (int j = t; j < m; j += 256) {            // compact winning bucket
      u32 ob = (u32)(ck[j] >> 24);
      u32 bk = (u32)(((u64)(ob - obL()) << 8) / span);
      if ((int)bk == W) {
        int p = atomicAdd(&sh_m2, 1);
        if (p < CAP2) ck2[p] = ck[j];
      }
    }
    __syncthreads();
    int m2 = sh_m2;
    if (m2 <= CAP2) {
      for (int j = t; j < m2; j += 256) {
        u64 key = ck2[j];
        int r = 0;
        for (int q = 0; q < m2; ++q) r += (ck2[q] < key);   // keys distinct
        if (r == krem3) ws->keysel[b] = key & 0x00FFFFFFFFFFFFFFull;  // strip b byte
      }
      return;
    }
    __syncthreads();   // sub-bucket overflow -> exact radix below
  }

  // exact in-block 8-bit radix select over segment [start, start+cnt)
  {
    int acc = 0;
    for (int blk = t; blk < nblk; blk += 256) {
      const u32* mrow = meta + (size_t)blk * MSTRIDE;
      for (int x = 0; x < b; ++x) acc += (int)mrow[x];
    }
    sc[t] = acc; __syncthreads();
    for (int off = 128; off > 0; off >>= 1) { if (t < off) sc[t] += sc[t + off]; __syncthreads(); }
    if (t == 0) sh_start = sc[0];
    __syncthreads();
  }
  int start = sh_start;
  u64 prefix = 0; int kr = krem;
  for (int shift = 48; shift >= 0; shift -= 8) {
    sc[t] = 0;
    __syncthreads();
    for (int idx = t; idx < cnt; idx += 256) {
      u64 key = ((u64)ordbits(scores[start + idx]) << 24) | (u32)(start + idx);
      if ((key >> (shift + 8)) == prefix) atomicAdd(&sc[(int)((key >> shift) & 255)], 1);
    }
    __syncthreads();
    int own = sc[t];
    for (int off = 1; off < 256; off <<= 1) {
      int v = (t >= off) ? sc[t - off] : 0;
      __syncthreads(); sc[t] += v; __syncthreads();
    }
    int excl = sc[t] - own;
    if (kr >= excl && kr < excl + own) { sh_w = t; sh_krem = kr - excl; }
    __syncthreads();
    prefix = (prefix << 8) | (u32)sh_w;
    kr = sh_krem;
    __syncthreads();
  }
  if (t == 0) ws->keysel[b] = prefix;
}

// ---------------- apply (global-idx keys; only keysel needed) ----------------
__global__ void k_apply(const f4* __restrict__ feats4,
                        const int* __restrict__ batch,
                        const float* __restrict__ scores,
                        const WsHdr* __restrict__ ws,
                        f4* __restrict__ out4, int n) {
  int t = threadIdx.x;
  int pl = t >> 4, ch = t & 15;
  int i = blockIdx.x * 16 + pl;
  if (i >= n) return;
  int b = batch[i];                         // 16-lane broadcast loads
  u64 key = ((u64)ordbits(scores[i]) << 24) | (u32)i;
  size_t off = (size_t)i * 16 + (size_t)ch;
  f4 v;
  if (key >= ws->keysel[b]) {
    v = __builtin_nontemporal_load(feats4 + off);
  } else {
    v = (f4){0.f, 0.f, 0.f, 0.f};
  }
  __builtin_nontemporal_store(v, out4 + off);
}

// ---------------- fallback chain (tiny ws): exact, global-idx keys ----------------

__global__ void k_zero_hdr(WsHdr* ws) {
  int t = threadIdx.x;
  if (t < NBATCH) ws->counts[t] = 0;
}

__global__ void k_hist_fb(const int* __restrict__ batch, int n, WsHdr* ws) {
  __shared__ int h[NBATCH];
  if (threadIdx.x < NBATCH) h[threadIdx.x] = 0;
  __syncthreads();
  int stride = gridDim.x * blockDim.x;
  for (int i = blockIdx.x * blockDim.x + threadIdx.x; i < n; i += stride)
    atomicAdd(&h[batch[i]], 1);
  __syncthreads();
  if (threadIdx.x < NBATCH) atomicAdd(&ws->counts[threadIdx.x], h[threadIdx.x]);
}

__global__ void k_select_fb(const float* __restrict__ scores, WsHdr* ws) {
  __shared__ u32 hist[256];
  __shared__ u64 sh_prefix;
  __shared__ int sh_krem, sh_start;
  int b = blockIdx.x, t = threadIdx.x;
  if (t == 0) {
    int acc = 0; for (int x = 0; x < b; ++x) acc += ws->counts[x];
    sh_start = acc; sh_prefix = 0ull; sh_krem = ws->counts[b] >> 1;
  }
  __syncthreads();
  int start = sh_start, cnt = ws->counts[b];
  if (cnt == 0) { if (t == 0) ws->keysel[b] = 0ull; return; }
  for (int shift = 48; shift >= 0; shift -= 8) {
    for (int j = t; j < 256; j += blockDim.x) hist[j] = 0;
    __syncthreads();
    u64 prefix = sh_prefix;
    for (int idx = t; idx < cnt; idx += blockDim.x) {
      u64 key = ((u64)ordbits(scores[start + idx]) << 24) | (u32)(start + idx);
      if ((key >> (shift + 8)) == prefix)
        atomicAdd(&hist[(u32)(key >> shift) & 255u], 1u);
    }
    __syncthreads();
    if (t == 0) {
      int krem = sh_krem;
      u32 cum = 0, sel = 255;
      for (int j = 0; j < 256; ++j) {
        u32 c = hist[j];
        if ((u32)krem < cum + c) { sel = (u32)j; krem -= (int)cum; break; }
        cum += c;
      }
      sh_prefix = (sh_prefix << 8) | sel;
      sh_krem = krem;
    }
    __syncthreads();
  }
  if (t == 0) ws->keysel[b] = sh_prefix;
}

extern "C" void kernel_launch(void* const* d_in, const int* in_sizes, int n_in,
                              void* d_out, int out_size, void* d_ws, size_t ws_size,
                              hipStream_t stream) {
  const float* feats  = (const float*)d_in[0];
  const int*   batch  = (const int*)d_in[1];
  const float* scores = (const float*)d_in[2];
  float* out = (float*)d_out;
  int n = in_sizes[1];
  WsHdr* ws = (WsHdr*)d_ws;

  int nblk = (n + BPTS - 1) / BPTS;
  const size_t meta_bytes = (size_t)nblk * MSTRIDE * sizeof(u32);
  const size_t cand_bytes = (size_t)nblk * CAP_BLK * sizeof(u64);
  const size_t need = sizeof(WsHdr) + meta_bytes + cand_bytes;

  if (ws_size >= need) {
    u32* meta = (u32*)((char*)d_ws + sizeof(WsHdr));
    u64* cand = (u64*)((char*)d_ws + sizeof(WsHdr) + meta_bytes);
    k_pass1<<<nblk, 256, 0, stream>>>(batch, scores, n, meta, cand);
    k_final<<<NBATCH, 256, 0, stream>>>(scores, meta, nblk, cand, ws);
  } else {
    k_zero_hdr <<<1, 64, 0, stream>>>(ws);
    k_hist_fb  <<<1024, 256, 0, stream>>>(batch, n, ws);
    k_select_fb<<<NBATCH, 256, 0, stream>>>(scores, ws);
  }

  int blocks = (n + 15) / 16;   // 16 rows per block, 16 float4 per row
  k_apply<<<blocks, 256, 0, stream>>>((const f4*)feats, batch, scores, ws,
                                      (f4*)out, n);
}

// Round 11
// 115.358 us; speedup vs baseline: 8.4839x; 1.1293x over previous
//
#include <hip/hip_runtime.h>
#include <stdint.h>

#define NBATCH 32
#define VPT    4
#define BPTS   1024            // points per pass1 block (256*VPT)
#define CAP_BLK 256            // candidate slots per block (expected ~82)
#define MSTRIDE 72             // u32s per block meta row: cnt[32] clo[32] candcnt pad[7]
#define CAPTOT 6144            // LDS gather capacity (expected ~2500/segment)
#define CAP2   512             // sub-bucket capacity in rank select
#define APPLY_BLOCKS 2048      // grid-stride apply (G11: cap ~8 blocks/CU)

typedef unsigned long long u64;
typedef unsigned int u32;
typedef float f4 __attribute__((ext_vector_type(4)));

struct WsHdr {
  u64 keysel[NBATCH];   // k-th smallest 56-bit key per segment (b-byte masked off)
  int counts[NBATCH];   // fallback path only
};
// ws: WsHdr | u32 meta[nblk*MSTRIDE] | u64 cand[nblk*CAP_BLK]
// Nothing is pre-zeroed: every meta row is fully written by its owning block;
// cand slots are only read up to the stored (clamped) count.

__device__ __forceinline__ u32 ordbits(float s) {
  u32 u = __float_as_uint(s);
  return (u & 0x80000000u) ? ~u : (u | 0x80000000u);
}
__device__ __forceinline__ u32 obL() { return ordbits(0.46f); }
__device__ __forceinline__ u32 obR() { return ordbits(0.54f); }

// ---------------- fast path (3 kernels, no zeroing, no global atomics) ------------

__global__ void k_pass1(const int* __restrict__ batch, const float* __restrict__ scores,
                        int n, u32* __restrict__ meta, u64* __restrict__ cand) {
  __shared__ int hc[NBATCH], hl[NBATCH];
  __shared__ int sc[256];
  int t = threadIdx.x, blk = blockIdx.x;
  if (t < NBATCH) { hc[t] = 0; hl[t] = 0; }
  __syncthreads();

  u64 wk[VPT]; int wcnt = 0;
  int i0 = blk * BPTS + t * VPT;
  #pragma unroll
  for (int v = 0; v < VPT; ++v) {
    int i = i0 + v;
    if (i < n) {
      int b = batch[i];
      u32 ob = ordbits(scores[i]);
      bool lo = ob < obL();
      u64 act = __ballot(1);
      int lead = (int)__ffsll((long long)act) - 1;
      int b0 = __shfl(b, lead, 64);
      bool uni = (__ballot(b == b0) == act);
      if (uni) {
        u64 lom = __ballot(lo);
        if ((t & 63) == lead) {
          atomicAdd(&hc[b0], (int)__popcll(act));
          if (lom) atomicAdd(&hl[b0], (int)__popcll(lom));
        }
      } else {
        atomicAdd(&hc[b], 1);
        if (lo) atomicAdd(&hl[b], 1);
      }
      if (!lo && ob < obR())
        wk[wcnt++] = ((u64)(u32)b << 56) | ((u64)ob << 24) | (u32)i;
    }
  }
  // block-wide compaction of window candidates (LDS scan, deterministic)
  sc[t] = wcnt; __syncthreads();
  for (int off = 1; off < 256; off <<= 1) {
    int v = (t >= off) ? sc[t - off] : 0;
    __syncthreads(); sc[t] += v; __syncthreads();
  }
  int excl = sc[t] - wcnt;
  int m = sc[255];
  u64* dst = cand + (size_t)blk * CAP_BLK;
  for (int j = 0; j < wcnt; ++j)
    if (excl + j < CAP_BLK) dst[excl + j] = wk[j];
  __syncthreads();
  u32* mrow = meta + (size_t)blk * MSTRIDE;
  if (t < NBATCH) { mrow[t] = (u32)hc[t]; mrow[NBATCH + t] = (u32)hl[t]; }
  if (t == 0) mrow[64] = (u32)m;              // true count (may exceed CAP_BLK)
}

// one block per segment: reduce meta, gather+filter candidates, bucket-rank.
// Exact in-block radix fallback for window miss / overflow (data-independent).
__global__ void k_final(const float* __restrict__ scores, const u32* __restrict__ meta,
                        int nblk, const u64* __restrict__ cand, WsHdr* ws) {
  __shared__ u64 ck[CAPTOT];     // 48KB
  __shared__ u64 ck2[CAP2];      // 4KB
  __shared__ int sc[256];
  __shared__ int sh_w, sh_krem, sh_m, sh_m2, sh_cnt, sh_clo, sh_bad, sh_start;
  int b = blockIdx.x, t = threadIdx.x;

  // reduce cnt/clo/bad over all pass1 blocks (thread-strided)
  {
    int c = 0, l = 0, bad = 0;
    for (int blk = t; blk < nblk; blk += 256) {
      const u32* mrow = meta + (size_t)blk * MSTRIDE;
      u32 cb = mrow[b];
      c += (int)cb;
      l += (int)mrow[NBATCH + b];
      if (cb && mrow[64] > CAP_BLK) bad = 1;
    }
    sc[t] = c; __syncthreads();
    for (int off = 128; off > 0; off >>= 1) { if (t < off) sc[t] += sc[t + off]; __syncthreads(); }
    if (t == 0) sh_cnt = sc[0];
    __syncthreads();
    sc[t] = l; __syncthreads();
    for (int off = 128; off > 0; off >>= 1) { if (t < off) sc[t] += sc[t + off]; __syncthreads(); }
    if (t == 0) sh_clo = sc[0];
    __syncthreads();
    sc[t] = bad; __syncthreads();
    for (int off = 128; off > 0; off >>= 1) { if (t < off) sc[t] |= sc[t + off]; __syncthreads(); }
    if (t == 0) { sh_bad = sc[0]; sh_m = 0; sh_m2 = 0; }
    __syncthreads();
  }
  int cnt = sh_cnt;
  if (cnt == 0) { if (t == 0) ws->keysel[b] = 0ull; return; }
  int krem = cnt >> 1;                        // ndrop = floor(cnt*0.5) exact

  // gather this segment's candidates (filter by top byte), thread-strided blocks
  for (int blk = t; blk < nblk; blk += 256) {
    const u32* mrow = meta + (size_t)blk * MSTRIDE;
    if (mrow[b] == 0) continue;               // no points of b in this block
    int cc = (int)mrow[64]; if (cc > CAP_BLK) cc = CAP_BLK;
    const u64* src = cand + (size_t)blk * CAP_BLK;
    for (int j = 0; j < cc; ++j) {
      u64 s = src[j];
      if ((int)(s >> 56) == b) {
        int p = atomicAdd(&sh_m, 1);
        if (p < CAPTOT) ck[p] = s;
      }
    }
  }
  __syncthreads();
  int m = sh_m;
  int krem2 = krem - sh_clo;
  bool fast = !sh_bad && m <= CAPTOT && krem2 >= 0 && krem2 < m;

  if (fast) {
    const u32 span = obR() - obL();
    sc[t] = 0; __syncthreads();
    for (int j = t; j < m; j += 256) {
      u32 ob = (u32)(ck[j] >> 24);
      u32 bk = (u32)(((u64)(ob - obL()) << 8) / span);
      atomicAdd(&sc[bk], 1);
    }
    __syncthreads();
    int own = sc[t];
    for (int off = 1; off < 256; off <<= 1) {     // Hillis-Steele inclusive scan
      int v = (t >= off) ? sc[t - off] : 0;
      __syncthreads(); sc[t] += v; __syncthreads();
    }
    int excl = sc[t] - own;
    if (krem2 >= excl && krem2 < excl + own) { sh_w = t; sh_krem = krem2 - excl; }
    __syncthreads();
    int W = sh_w, krem3 = sh_krem;
    for (int j = t; j < m; j += 256) {            // compact winning bucket
      u32 ob = (u32)(ck[j] >> 24);
      u32 bk = (u32)(((u64)(ob - obL()) << 8) / span);
      if ((int)bk == W) {
        int p = atomicAdd(&sh_m2, 1);
        if (p < CAP2) ck2[p] = ck[j];
      }
    }
    __syncthreads();
    int m2 = sh_m2;
    if (m2 <= CAP2) {
      for (int j = t; j < m2; j += 256) {
        u64 key = ck2[j];
        int r = 0;
        for (int q = 0; q < m2; ++q) r += (ck2[q] < key);   // keys distinct
        if (r == krem3) ws->keysel[b] = key & 0x00FFFFFFFFFFFFFFull;  // strip b byte
      }
      return;
    }
    __syncthreads();   // sub-bucket overflow -> exact radix below
  }

  // exact in-block 8-bit radix select over segment [start, start+cnt)
  {
    int acc = 0;
    for (int blk = t; blk < nblk; blk += 256) {
      const u32* mrow = meta + (size_t)blk * MSTRIDE;
      for (int x = 0; x < b; ++x) acc += (int)mrow[x];
    }
    sc[t] = acc; __syncthreads();
    for (int off = 128; off > 0; off >>= 1) { if (t < off) sc[t] += sc[t + off]; __syncthreads(); }
    if (t == 0) sh_start = sc[0];
    __syncthreads();
  }
  int start = sh_start;
  u64 prefix = 0; int kr = krem;
  for (int shift = 48; shift >= 0; shift -= 8) {
    sc[t] = 0;
    __syncthreads();
    for (int idx = t; idx < cnt; idx += 256) {
      u64 key = ((u64)ordbits(scores[start + idx]) << 24) | (u32)(start + idx);
      if ((key >> (shift + 8)) == prefix) atomicAdd(&sc[(int)((key >> shift) & 255)], 1);
    }
    __syncthreads();
    int own = sc[t];
    for (int off = 1; off < 256; off <<= 1) {
      int v = (t >= off) ? sc[t - off] : 0;
      __syncthreads(); sc[t] += v; __syncthreads();
    }
    int excl = sc[t] - own;
    if (kr >= excl && kr < excl + own) { sh_w = t; sh_krem = kr - excl; }
    __syncthreads();
    prefix = (prefix << 8) | (u32)sh_w;
    kr = sh_krem;
    __syncthreads();
  }
  if (t == 0) ws->keysel[b] = prefix;
}

// ---------------- apply: grid-stride (2048 blocks), same coalescing ----------------
__global__ void k_apply(const f4* __restrict__ feats4,
                        const int* __restrict__ batch,
                        const float* __restrict__ scores,
                        const WsHdr* __restrict__ ws,
                        f4* __restrict__ out4, int n) {
  int t = threadIdx.x;
  int pl = t >> 4, ch = t & 15;
  int rstride = gridDim.x * 16;             // rows per grid sweep
  for (int i = blockIdx.x * 16 + pl; i < n; i += rstride) {
    int b = batch[i];                       // 16-lane broadcast loads
    u64 key = ((u64)ordbits(scores[i]) << 24) | (u32)i;
    size_t off = (size_t)i * 16 + (size_t)ch;
    f4 v;
    if (key >= ws->keysel[b]) {
      v = __builtin_nontemporal_load(feats4 + off);
    } else {
      v = (f4){0.f, 0.f, 0.f, 0.f};
    }
    __builtin_nontemporal_store(v, out4 + off);
  }
}

// ---------------- fallback chain (tiny ws): exact, global-idx keys ----------------

__global__ void k_zero_hdr(WsHdr* ws) {
  int t = threadIdx.x;
  if (t < NBATCH) ws->counts[t] = 0;
}

__global__ void k_hist_fb(const int* __restrict__ batch, int n, WsHdr* ws) {
  __shared__ int h[NBATCH];
  if (threadIdx.x < NBATCH) h[threadIdx.x] = 0;
  __syncthreads();
  int stride = gridDim.x * blockDim.x;
  for (int i = blockIdx.x * blockDim.x + threadIdx.x; i < n; i += stride)
    atomicAdd(&h[batch[i]], 1);
  __syncthreads();
  if (threadIdx.x < NBATCH) atomicAdd(&ws->counts[threadIdx.x], h[threadIdx.x]);
}

__global__ void k_select_fb(const float* __restrict__ scores, WsHdr* ws) {
  __shared__ u32 hist[256];
  __shared__ u64 sh_prefix;
  __shared__ int sh_krem, sh_start;
  int b = blockIdx.x, t = threadIdx.x;
  if (t == 0) {
    int acc = 0; for (int x = 0; x < b; ++x) acc += ws->counts[x];
    sh_start = acc; sh_prefix = 0ull; sh_krem = ws->counts[b] >> 1;
  }
  __syncthreads();
  int start = sh_start, cnt = ws->counts[b];
  if (cnt == 0) { if (t == 0) ws->keysel[b] = 0ull; return; }
  for (int shift = 48; shift >= 0; shift -= 8) {
    for (int j = t; j < 256; j += blockDim.x) hist[j] = 0;
    __syncthreads();
    u64 prefix = sh_prefix;
    for (int idx = t; idx < cnt; idx += blockDim.x) {
      u64 key = ((u64)ordbits(scores[start + idx]) << 24) | (u32)(start + idx);
      if ((key >> (shift + 8)) == prefix)
        atomicAdd(&hist[(u32)(key >> shift) & 255u], 1u);
    }
    __syncthreads();
    if (t == 0) {
      int krem = sh_krem;
      u32 cum = 0, sel = 255;
      for (int j = 0; j < 256; ++j) {
        u32 c = hist[j];
        if ((u32)krem < cum + c) { sel = (u32)j; krem -= (int)cum; break; }
        cum += c;
      }
      sh_prefix = (sh_prefix << 8) | sel;
      sh_krem = krem;
    }
    __syncthreads();
  }
  if (t == 0) ws->keysel[b] = sh_prefix;
}

extern "C" void kernel_launch(void* const* d_in, const int* in_sizes, int n_in,
                              void* d_out, int out_size, void* d_ws, size_t ws_size,
                              hipStream_t stream) {
  const float* feats  = (const float*)d_in[0];
  const int*   batch  = (const int*)d_in[1];
  const float* scores = (const float*)d_in[2];
  float* out = (float*)d_out;
  int n = in_sizes[1];
  WsHdr* ws = (WsHdr*)d_ws;

  int nblk = (n + BPTS - 1) / BPTS;
  const size_t meta_bytes = (size_t)nblk * MSTRIDE * sizeof(u32);
  const size_t cand_bytes = (size_t)nblk * CAP_BLK * sizeof(u64);
  const size_t need = sizeof(WsHdr) + meta_bytes + cand_bytes;

  if (ws_size >= need) {
    u32* meta = (u32*)((char*)d_ws + sizeof(WsHdr));
    u64* cand = (u64*)((char*)d_ws + sizeof(WsHdr) + meta_bytes);
    k_pass1<<<nblk, 256, 0, stream>>>(batch, scores, n, meta, cand);
    k_final<<<NBATCH, 256, 0, stream>>>(scores, meta, nblk, cand, ws);
  } else {
    k_zero_hdr <<<1, 64, 0, stream>>>(ws);
    k_hist_fb  <<<1024, 256, 0, stream>>>(batch, n, ws);
    k_select_fb<<<NBATCH, 256, 0, stream>>>(scores, ws);
  }

  int blocks = (n + 15) / 16;
  if (blocks > APPLY_BLOCKS) blocks = APPLY_BLOCKS;   // grid-stride the rest
  k_apply<<<blocks, 256, 0, stream>>>((const f4*)feats, batch, scores, ws,
                                      (f4*)out, n);
}